// Round 1
// 507.462 us; speedup vs baseline: 1.0266x; 1.0266x over previous
//
#include <hip/hip_runtime.h>
#include <math.h>

#define B_    1024
#define N_    512
#define M_    128
#define CDIM_ 1024
#define OUT_  390   // 3*M + 6
#define OUTP_ 448   // padded OUT (7 * 64)
#define SPLITK 4
#define KCH   (CDIM_ / SPLITK)   // 256

__device__ __forceinline__ float softplus_f(float x) {
    return fmaxf(x, 0.f) + log1pf(expf(-fabsf(x)));
}
__device__ __forceinline__ float sigmoid_f(float x) {
    return 1.f / (1.f + expf(-x));
}

// ---------------------------------------------------------------------------
// Kernel 1: split-K SGEMM partials: part[s][b][j] = sum_{k in chunk s} hid*W
// 64x64 tile, 256 threads, 4x4 per thread, 16-deep k subtiles.
// Grid (16, 7, 4) = 448 blocks.
// ---------------------------------------------------------------------------
__global__ __launch_bounds__(256) void fc_kernel(
    const float* __restrict__ hid, const float* __restrict__ W_fc,
    float* __restrict__ part)
{
    // stride 68 floats: 272 B keeps float4 alignment (272 % 16 == 0) and
    // gives 2-way (free) bank aliasing on the transposed stores.
    __shared__ float As[16][68];
    __shared__ float Bs[16][68];

    const int tid = threadIdx.x;
    const int bm = blockIdx.x, bn = blockIdx.y, bk = blockIdx.z;
    const int rb = bm * 64;          // hid row base
    const int jb = bn * 64;          // out-col base (W_fc row base)
    const int kb = bk * KCH;         // k base

    const int tx = tid & 15;         // 0..15 -> 4 cols each
    const int ty = tid >> 4;         // 0..15 -> 4 rows each

    const int srow = tid >> 2;       // 0..63  staging row
    const int scol = (tid & 3) * 4;  // 0,4,8,12 staging k-offset

    const int arow = rb + srow;
    const int jrow = jb + srow;
    const bool jvalid = (jrow < OUT_);

    float acc[4][4];
#pragma unroll
    for (int r = 0; r < 4; ++r)
#pragma unroll
        for (int c = 0; c < 4; ++c) acc[r][c] = 0.f;

    for (int kt = 0; kt < KCH; kt += 16) {
        float4 av = *(const float4*)(hid + (size_t)arow * CDIM_ + kb + kt + scol);
        float4 bv = make_float4(0.f, 0.f, 0.f, 0.f);
        if (jvalid)
            bv = *(const float4*)(W_fc + (size_t)jrow * CDIM_ + kb + kt + scol);
        As[scol + 0][srow] = av.x; As[scol + 1][srow] = av.y;
        As[scol + 2][srow] = av.z; As[scol + 3][srow] = av.w;
        Bs[scol + 0][srow] = bv.x; Bs[scol + 1][srow] = bv.y;
        Bs[scol + 2][srow] = bv.z; Bs[scol + 3][srow] = bv.w;
        __syncthreads();
#pragma unroll
        for (int k = 0; k < 16; ++k) {
            float4 a = *(const float4*)&As[k][ty * 4];
            float4 b = *(const float4*)&Bs[k][tx * 4];
            float ar[4] = {a.x, a.y, a.z, a.w};
            float br[4] = {b.x, b.y, b.z, b.w};
#pragma unroll
            for (int r = 0; r < 4; ++r)
#pragma unroll
                for (int c = 0; c < 4; ++c)
                    acc[r][c] += ar[r] * br[c];
        }
        __syncthreads();
    }

    float* pbase = part + (size_t)bk * B_ * OUTP_;
#pragma unroll
    for (int r = 0; r < 4; ++r) {
        float4 v = make_float4(acc[r][0], acc[r][1], acc[r][2], acc[r][3]);
        *(float4*)(pbase + (size_t)(rb + ty * 4 + r) * OUTP_ + jb + tx * 4) = v;
    }
}

// ---------------------------------------------------------------------------
// Kernel 2: sum split-K partials + bias + activations. One block (128 thr)/b.
// splits: k=[0:128], beta=128, g=129, s=130:133, gamma=133, e=134:262,
//         a=262:390
// ---------------------------------------------------------------------------
__global__ __launch_bounds__(128) void act_kernel(
    const float* __restrict__ part, const float* __restrict__ b_fc,
    float* __restrict__ ws_k, float* __restrict__ ws_e,
    float* __restrict__ ws_a, float* __restrict__ params)
{
    const int b = blockIdx.x;
    const int tid = threadIdx.x;   // 0..127
    const float* pb = part + (size_t)b * OUTP_;
    const size_t S = (size_t)B_ * OUTP_;

    float vk = b_fc[tid];
    float ve = b_fc[134 + tid];
    float va = b_fc[262 + tid];
#pragma unroll
    for (int s = 0; s < SPLITK; ++s) {
        vk += pb[s * S + tid];
        ve += pb[s * S + 134 + tid];
        va += pb[s * S + 262 + tid];
    }
    vk += 1e-16f;
    ws_k[(size_t)b * M_ + tid] = vk;
    ws_e[(size_t)b * M_ + tid] = sigmoid_f(ve);
    ws_a[(size_t)b * M_ + tid] = va;

    float sq = vk * vk;
#pragma unroll
    for (int mask = 1; mask < 64; mask <<= 1) sq += __shfl_xor(sq, mask);
    __shared__ float red[2];
    __shared__ float sscal[6];
    if ((tid & 63) == 0) red[tid >> 6] = sq;
    if (tid < 6) {
        float v = b_fc[128 + tid];
#pragma unroll
        for (int s = 0; s < SPLITK; ++s) v += pb[s * S + 128 + tid];
        sscal[tid] = v;
    }
    __syncthreads();
    if (tid == 0) {
        float knorm = sqrtf(red[0] + red[1]);
        float beta  = softplus_f(sscal[0]);
        float g     = sigmoid_f(sscal[1]);
        float x0 = sscal[2], x1 = sscal[3], x2 = sscal[4];
        float mx = fmaxf(x0, fmaxf(x1, x2));
        float e0 = expf(x0 - mx), e1 = expf(x1 - mx), e2 = expf(x2 - mx);
        float inv = 1.f / (e0 + e1 + e2);
        float gamma = 1.f + softplus_f(sscal[5]);
        float* p = params + (size_t)b * 8;
        p[0] = beta; p[1] = g; p[2] = e0 * inv; p[3] = e1 * inv;
        p[4] = e2 * inv; p[5] = gamma; p[6] = knorm;
    }
}

// ---------------------------------------------------------------------------
// Helper: partial dot & normsq over 8 contiguous floats of a memory row.
// ---------------------------------------------------------------------------
__device__ __forceinline__ void row_partial(float4 xa, float4 xb,
                                            const float kd[8],
                                            float& dot, float& nrm)
{
    float xv[8] = {xa.x, xa.y, xa.z, xa.w, xb.x, xb.y, xb.z, xb.w};
    dot = 0.f; nrm = 0.f;
#pragma unroll
    for (int t = 0; t < 8; ++t) {
        float m = xv[t] + 1e-16f;
        dot += m * kd[t];
        nrm += m * m;
    }
}

// ---------------------------------------------------------------------------
// Kernel 3 (fused): content+location addressing, then erase/add write.
// One block per b; 512 threads (8 waves). With grid == B == 1024 blocks the
// scheduler places 4 blocks/CU -> 32 waves/CU (100% occupancy ceiling vs 50%
// at 256 threads). __launch_bounds__(512, 8) pins VGPR <= 64 so 8 waves/SIMD
// actually fit.
// Phase 1: 16 lanes/row, 8 contiguous floats/lane; rows processed 2 at a time
//          so the two 4-step shuffle chains interleave (ILP) and 4 float4
//          loads are in flight per iteration.
// Phase 2/3: softmax over N (1 value/thread), interpolate, shift, sharpen.
// Phase 4: re-stream this b's memory slice (L3-warm) + erase/add write.
//          e/a fragments are loop-invariant per thread -> hoisted.
// ---------------------------------------------------------------------------
__global__ __launch_bounds__(512, 8) void addr_write_kernel(
    const float* __restrict__ memory, const float* __restrict__ w_pre,
    const float* __restrict__ ws_k, const float* __restrict__ ws_e,
    const float* __restrict__ ws_a, const float* __restrict__ params,
    float* __restrict__ w_out, float* __restrict__ mem_out)
{
    const int b = blockIdx.x;
    const int tid = threadIdx.x;     // 0..511
    const int lane = tid & 63;
    const int wave = tid >> 6;       // 0..7

    __shared__ __align__(16) float k_s[M_];
    __shared__ __align__(16) float e_s[M_];
    __shared__ __align__(16) float a_s[M_];
    __shared__ float Ks[N_];
    __shared__ float wgs[N_];
    __shared__ float ws_f[N_];
    __shared__ float red[16];

    if (tid < M_) {
        k_s[tid] = ws_k[(size_t)b * M_ + tid];
        e_s[tid] = ws_e[(size_t)b * M_ + tid];
        a_s[tid] = ws_a[(size_t)b * M_ + tid];
    }

    // per-b scalars: uniform address -> scalar loads, live in SGPRs
    const float* p = params + (size_t)b * 8;
    const float beta = p[0], g = p[1], s0 = p[2], s1 = p[3], s2 = p[4];
    const float gamma = p[5], knorm = p[6];

    __syncthreads();

    // --- phase 1: dot + normsq; 16 lanes/row, 4 rows per wave-iter,
    //     2 iterations batched for load/shuffle ILP ---
    const int sub = lane >> 4;       // 0..3: row within group of 4
    const int j16 = lane & 15;       // 0..15: 8-float chunk within row
    float kd[8];
#pragma unroll
    for (int t = 0; t < 8; ++t) kd[t] = k_s[j16 * 8 + t];

    const float* mb = memory + (size_t)b * N_ * M_;
    const int rbase = wave * 64 + sub;
    for (int ii = 0; ii < 16; ii += 2) {
        const int n0 = rbase + ii * 4;
        const int n1 = n0 + 4;
        const float* r0 = mb + (size_t)n0 * M_ + j16 * 8;
        const float* r1 = mb + (size_t)n1 * M_ + j16 * 8;
        float4 x0a = *(const float4*)(r0);
        float4 x0b = *(const float4*)(r0 + 4);
        float4 x1a = *(const float4*)(r1);
        float4 x1b = *(const float4*)(r1 + 4);

        float d0, q0, d1, q1;
        row_partial(x0a, x0b, kd, d0, q0);
        row_partial(x1a, x1b, kd, d1, q1);
#pragma unroll
        for (int mask = 1; mask < 16; mask <<= 1) {
            d0 += __shfl_xor(d0, mask);
            q0 += __shfl_xor(q0, mask);
            d1 += __shfl_xor(d1, mask);
            q1 += __shfl_xor(q1, mask);
        }
        if (j16 == 0) {
            Ks[n0] = beta * (d0 / fmaxf(sqrtf(q0) * knorm, 1e-8f));
            Ks[n1] = beta * (d1 / fmaxf(sqrtf(q1) * knorm, 1e-8f));
        }
    }
    __syncthreads();

    // --- phase 2: softmax over N=512 (1 value per thread) ---
    float v = Ks[tid];
    float mx = v;
#pragma unroll
    for (int mask = 1; mask < 64; mask <<= 1) mx = fmaxf(mx, __shfl_xor(mx, mask));
    if (lane == 0) red[wave] = mx;
    __syncthreads();
    mx = red[0];
#pragma unroll
    for (int w2 = 1; w2 < 8; ++w2) mx = fmaxf(mx, red[w2]);

    float pv = expf(v - mx);
    float sm = pv;
#pragma unroll
    for (int mask = 1; mask < 64; mask <<= 1) sm += __shfl_xor(sm, mask);
    if (lane == 0) red[8 + wave] = sm;
    __syncthreads();
    float tot = 0.f;
#pragma unroll
    for (int w2 = 0; w2 < 8; ++w2) tot += red[8 + w2];
    const float inv = 1.f / tot;

    float wp = w_pre[(size_t)b * N_ + tid];
    float wg = g * (pv * inv) + (1.f - g) * wp;
    wgs[tid] = wg;
    __syncthreads();

    // --- phase 3: circular shift + sharpen + renormalize ---
    float t3 = s0 * wgs[(tid + 511) & 511] + s1 * wg + s2 * wgs[(tid + 1) & 511];
    float sh = powf(t3, gamma);
    float ssum = sh;
#pragma unroll
    for (int mask = 1; mask < 64; mask <<= 1) ssum += __shfl_xor(ssum, mask);
    if (lane == 0) red[wave] = ssum;
    __syncthreads();
    float wsum = 0.f;
#pragma unroll
    for (int w2 = 0; w2 < 8; ++w2) wsum += red[w2];
    const float winv = 1.f / (wsum + 1e-16f);

    float wf = sh * winv;
    w_out[(size_t)b * N_ + tid] = wf;
    ws_f[tid] = wf;
    __syncthreads();

    // --- phase 4: erase/add write, float4 streaming over this b's slice ---
    const float4* min4 = (const float4*)(mb);
    float4* mout4 = (float4*)(mem_out + (size_t)b * N_ * M_);
    const float4 ev = ((const float4*)e_s)[tid & 31];   // loop-invariant
    const float4 av = ((const float4*)a_s)[tid & 31];   // loop-invariant
    const int nb = tid >> 5;                            // 0..15
    for (int i = 0; i < 32; i += 2) {
        const int i0 = i * 512 + tid;
        const int i1 = (i + 1) * 512 + tid;
        float4 m0 = min4[i0];
        float4 m1 = min4[i1];
        float w0 = ws_f[i * 16 + nb];
        float w1 = ws_f[(i + 1) * 16 + nb];
        float4 o0, o1;
        o0.x = m0.x * (1.f - w0 * ev.x) + w0 * av.x;
        o0.y = m0.y * (1.f - w0 * ev.y) + w0 * av.y;
        o0.z = m0.z * (1.f - w0 * ev.z) + w0 * av.z;
        o0.w = m0.w * (1.f - w0 * ev.w) + w0 * av.w;
        o1.x = m1.x * (1.f - w1 * ev.x) + w1 * av.x;
        o1.y = m1.y * (1.f - w1 * ev.y) + w1 * av.y;
        o1.z = m1.z * (1.f - w1 * ev.z) + w1 * av.z;
        o1.w = m1.w * (1.f - w1 * ev.w) + w1 * av.w;
        mout4[i0] = o0;
        mout4[i1] = o1;
    }
}

// ---------------------------------------------------------------------------
extern "C" void kernel_launch(void* const* d_in, const int* in_sizes, int n_in,
                              void* d_out, int out_size, void* d_ws, size_t ws_size,
                              hipStream_t stream)
{
    const float* hid    = (const float*)d_in[0];
    const float* w_pre  = (const float*)d_in[1];
    const float* memory = (const float*)d_in[2];
    const float* W_fc   = (const float*)d_in[3];
    const float* b_fc   = (const float*)d_in[4];

    float* out     = (float*)d_out;
    float* w_out   = out;                          // [B, N]
    float* mem_out = out + (size_t)B_ * N_;        // [B, N, M]

    float* ws     = (float*)d_ws;
    float* part   = ws;                                  // SPLITK*B*OUTP_
    float* ws_k   = part + (size_t)SPLITK * B_ * OUTP_;
    float* ws_e   = ws_k + (size_t)B_ * M_;
    float* ws_a   = ws_e + (size_t)B_ * M_;
    float* params = ws_a + (size_t)B_ * M_;              // B*8

    dim3 g1(B_ / 64, OUTP_ / 64, SPLITK);     // 16 x 7 x 4 = 448 blocks
    fc_kernel<<<g1, 256, 0, stream>>>(hid, W_fc, part);
    act_kernel<<<B_, 128, 0, stream>>>(part, b_fc, ws_k, ws_e, ws_a, params);
    addr_write_kernel<<<B_, 512, 0, stream>>>(memory, w_pre, ws_k, ws_e, ws_a,
                                              params, w_out, mem_out);
}